// Round 14
// baseline (48.612 us; speedup 1.0000x reference)
//
#include <hip/hip_runtime.h>
#include <hip/hip_bf16.h>

#define BB 8
#define NN 256
#define CC 32
#define LL 4
#define BN (BB*NN)          // 2048
#define LC (LL*CC)          // 128

typedef short short8 __attribute__((ext_vector_type(8)));
typedef float f32x4 __attribute__((ext_vector_type(4)));

union U8 { short8 s; unsigned u[4]; };

__device__ inline unsigned pkbf(float a, float b){
    __hip_bfloat162 h = __float22bfloat162_rn(make_float2(a, b));
    union { __hip_bfloat162 h2; unsigned u; } cv; cv.h2 = h; return cv.u;
}

// ---------------- Kernel 0: init — zero pooled accumulators, pack Rw2/Wv ----------------
__global__ __launch_bounds__(256) void so3_init(
    const float* __restrict__ Rw2,    // (32,128)
    const float* __restrict__ Wv,     // (L,4,32)
    float* __restrict__ pmaxg,        // (B,128) -> 0
    float* __restrict__ psumg,        // (B,128) -> 0
    short* __restrict__ RW2bf,        // (128,32) bf16 [col][k]
    float* __restrict__ WvT)          // (128,4)  [col][d]
{
    const int t = threadIdx.x;
    #pragma unroll
    for (int rr = 0; rr < 4; ++rr) {
        pmaxg[rr*256 + t] = 0.f;
        psumg[rr*256 + t] = 0.f;
    }
    {
        const int col = t >> 1, kh = (t & 1) * 16;
        unsigned uu[8];
        #pragma unroll
        for (int q = 0; q < 8; ++q)
            uu[q] = pkbf(Rw2[(kh + 2*q)*LC + col], Rw2[(kh + 2*q + 1)*LC + col]);
        *(uint4*)&RW2bf[col*32 + kh]     = make_uint4(uu[0], uu[1], uu[2], uu[3]);
        *(uint4*)&RW2bf[col*32 + kh + 8] = make_uint4(uu[4], uu[5], uu[6], uu[7]);
    }
    if (t < 128) {
        const int l = t >> 5, c = t & 31;
        float4 o;
        o.x = Wv[l*128 +       c];
        o.y = Wv[l*128 +  32 + c];
        o.z = Wv[l*128 +  64 + c];
        o.w = Wv[l*128 +  96 + c];
        *(float4*)&WvT[t*4] = o;
    }
}

// ---- helper: compute Y from direction and stage alpha*Y into a slab ----
__device__ inline void stage_aY(short* __restrict__ slab, int j, float a,
                                float dx, float dy, float dz, float r2)
{
    const float ir = rsqrtf(r2);
    const float ux = dx*ir, uy = dy*ir, uz = dz*ir;
    const float X2 = ux*ux, Y2 = uy*uy, Z2 = uz*uz;
    const float y0  = 0.28209479f;
    const float y1  = 0.48860251f*uy, y2 = 0.48860251f*uz, y3 = 0.48860251f*ux;
    const float y4  = 1.09254843f*ux*uy;
    const float y5  = 1.09254843f*uy*uz;
    const float y6  = 0.31539157f*(3.f*Z2 - 1.f);
    const float y7  = 1.09254843f*ux*uz;
    const float y8  = 0.54627422f*(X2 - Y2);
    const float y9  = 0.59004359f*uy*(3.f*X2 - Y2);
    const float y10 = 2.89061144f*ux*uy*uz;
    const float y11 = 0.45704579f*uy*(5.f*Z2 - 1.f);
    const float y12 = 0.37317633f*uz*(5.f*Z2 - 3.f);
    const float y13 = 0.45704579f*ux*(5.f*Z2 - 1.f);
    const float y14 = 1.44530572f*uz*(X2 - Y2);
    const float y15 = 0.59004359f*ux*(X2 - 3.f*Y2);
    #define ST2(mm, va, vb) { unsigned uu = pkbf((va)*a, (vb)*a); \
        slab[(mm)*264 + j] = (short)(uu & 0xffff); slab[(mm+1)*264 + j] = (short)(uu >> 16); }
    ST2(0,  y0,  y1)  ST2(2,  y2,  y3)
    ST2(4,  y4,  y5)  ST2(6,  y6,  y7)
    ST2(8,  y8,  y9)  ST2(10, y10, y11)
    ST2(12, y12, y13) ST2(14, y14, y15)
    #undef ST2
}

// ---------------- Kernel B: fused per-(b, i-pair), 4 waves, dual-i ILP ----------------
__global__ __launch_bounds__(256) void so3_main(
    const float* __restrict__ xg,     // (B,N,4)
    const float* __restrict__ Wq,     // (4,32)
    const float* __restrict__ Wk,     // (4,32)
    const float* __restrict__ Rw1,    // (32)
    const float* __restrict__ Rb1,    // (32)
    const short* __restrict__ RW2bf,  // (128,32) bf16
    const float* __restrict__ Rb2,    // (128)
    const float* __restrict__ WvT,    // (128,4)
    float* __restrict__ pmaxg,        // (B,128)
    float* __restrict__ psumg)        // (B,128)
{
    const int tid = threadIdx.x;          // 0..255
    const int blk = blockIdx.x;           // b*128 + ipair
    const int b = blk >> 7;
    const int i0 = (blk & 127) << 1;      // first i of the pair
    const int rowbase = b * NN;
    const int lane = tid & 63;
    const int w = tid >> 6;               // wave 0..3
    const int wcol = w & 1;               // column half
    const int jhalf = w >> 1;             // j half
    const int n = lane & 15;
    const int g = lane >> 4;
    const int kbase = g * 8;

    __shared__ short xsbf[NN*4];          // 2 KB
    __shared__ short aY0[16*264];         // 8448 B
    __shared__ short aY1[16*264];         // 8448 B
    __shared__ float r_lds[2][NN];        // 2 KB
    __shared__ float red[24];
    __shared__ float ssum_lds[2][LC];     // 1 KB

    // ---- own x row + both center rows ----
    const float4 x4  = *(const float4*)&xg[(rowbase + tid)*4];
    const float4 xi0 = *(const float4*)&xg[(rowbase + i0)*4];
    const float4 xi1 = *(const float4*)&xg[(rowbase + i0 + 1)*4];
    {
        uint2 xb;
        xb.x = pkbf(x4.x, x4.y);
        xb.y = pkbf(x4.z, x4.w);
        *(uint2*)&xsbf[tid*4] = xb;
    }
    const float dx0 = x4.x - xi0.x, dy0 = x4.y - xi0.y, dz0 = x4.z - xi0.z;
    const float r20 = dx0*dx0 + dy0*dy0 + dz0*dz0 + 1e-8f;
    r_lds[0][tid] = sqrtf(r20);
    const float dx1 = x4.x - xi1.x, dy1 = x4.y - xi1.y, dz1 = x4.z - xi1.z;
    const float r21 = dx1*dx1 + dy1*dy1 + dz1*dz1 + 1e-8f;
    r_lds[1][tid] = sqrtf(r21);

    // ---- waves 0/1: m[d] for i0/i1 -> red[8..11] / red[12..15] ----
    if (w < 2) {
        const float4 xi = (w == 0) ? xi0 : xi1;
        const int c = lane & 31;
        const float qc = xi.x*Wq[c] + xi.y*Wq[32+c] + xi.z*Wq[64+c] + xi.w*Wq[96+c];
        float md0 = qc * Wk[c];
        float md1 = qc * Wk[32+c];
        float md2 = qc * Wk[64+c];
        float md3 = qc * Wk[96+c];
        #pragma unroll
        for (int off = 16; off >= 1; off >>= 1) {
            md0 += __shfl_xor(md0, off);
            md1 += __shfl_xor(md1, off);
            md2 += __shfl_xor(md2, off);
            md3 += __shfl_xor(md3, off);
        }
        if (lane == 0) {
            const float lscale = 0.17677669529663687f;  // 1/sqrt(32)
            red[8 + 4*w]  = md0 * lscale;
            red[9 + 4*w]  = md1 * lscale;
            red[10 + 4*w] = md2 * lscale;
            red[11 + 4*w] = md3 * lscale;
        }
    }
    __syncthreads();   // xsbf, r_lds, red[8..15] ready

    // ---- logits for both i's; two-stage softmax (interleaved) ----
    const float lg0 = red[8]*x4.x  + red[9]*x4.y  + red[10]*x4.z + red[11]*x4.w;
    const float lg1 = red[12]*x4.x + red[13]*x4.y + red[14]*x4.z + red[15]*x4.w;
    float mx0 = lg0, mx1 = lg1;
    #pragma unroll
    for (int off = 32; off >= 1; off >>= 1) {
        mx0 = fmaxf(mx0, __shfl_xor(mx0, off));
        mx1 = fmaxf(mx1, __shfl_xor(mx1, off));
    }
    const float e0 = __expf(lg0 - mx0);
    const float e1 = __expf(lg1 - mx1);
    float sw0 = e0, sw1 = e1;
    #pragma unroll
    for (int off = 32; off >= 1; off >>= 1) {
        sw0 += __shfl_xor(sw0, off);
        sw1 += __shfl_xor(sw1, off);
    }
    if (lane == 0) {
        red[w] = mx0;  red[4+w]  = sw0;
        red[16+w] = mx1; red[20+w] = sw1;
    }
    __syncthreads();
    const float M0 = fmaxf(fmaxf(red[0], red[1]), fmaxf(red[2], red[3]));
    const float t0 = __expf(red[0]-M0)*red[4] + __expf(red[1]-M0)*red[5]
                   + __expf(red[2]-M0)*red[6] + __expf(red[3]-M0)*red[7];
    const float alpha0 = e0 * __expf(mx0 - M0) / t0;
    const float M1 = fmaxf(fmaxf(red[16], red[17]), fmaxf(red[18], red[19]));
    const float t1 = __expf(red[16]-M1)*red[20] + __expf(red[17]-M1)*red[21]
                   + __expf(red[18]-M1)*red[22] + __expf(red[19]-M1)*red[23];
    const float alpha1 = e1 * __expf(mx1 - M1) / t1;

    // ---- stage both aY slabs ----
    stage_aY(aY0, tid, alpha0, dx0, dy0, dz0, r20);
    stage_aY(aY1, tid, alpha1, dx1, dy1, dz1, r21);

    // ---- hoisted fragments (shared by both i's) ----
    float rw1q[8], rb1q[8];
    #pragma unroll
    for (int q = 0; q < 8; ++q) { rw1q[q] = Rw1[kbase+q]; rb1q[q] = Rb1[kbase+q]; }

    short8 bfrag[4];
    f32x4 cinit[4];
    short8 bv[4];
    const int colbase = wcol * 64;
    #pragma unroll
    for (int t4 = 0; t4 < 4; ++t4) {
        const int col = colbase + t4*16 + n;
        bfrag[t4] = *(const short8*)&RW2bf[col*32 + kbase];
        const float rb = Rb2[col];
        cinit[t4] = (f32x4){rb, rb, rb, rb};
        U8 z; z.u[0] = 0; z.u[1] = 0; z.u[2] = 0; z.u[3] = 0;
        if (g == 0) {
            const float4 f = *(const float4*)&WvT[col*4];
            z.u[0] = pkbf(f.x, f.y);
            z.u[1] = pkbf(f.z, f.w);
        }
        bv[t4] = z.s;
    }

    const int boff = n*264 + 4*g;

    __syncthreads();   // aY slabs ready; loop is barrier-free

    f32x4 acc0[4] = {}, acc1[4] = {};
    const f32x4 vzero = {0.f, 0.f, 0.f, 0.f};

    #pragma unroll
    for (int tt = 0; tt < 4; ++tt) {
        const int j0 = jhalf*128 + tt*32;

        const uint2 b0lo = *(const uint2*)&aY0[boff + j0];
        const uint2 b0hi = *(const uint2*)&aY0[boff + j0 + 16];
        const uint2 b1lo = *(const uint2*)&aY1[boff + j0];
        const uint2 b1hi = *(const uint2*)&aY1[boff + j0 + 16];
        U8 bf20, bf21;
        bf20.u[0] = b0lo.x; bf20.u[1] = b0lo.y; bf20.u[2] = b0hi.x; bf20.u[3] = b0hi.y;
        bf21.u[0] = b1lo.x; bf21.u[1] = b1lo.y; bf21.u[2] = b1hi.x; bf21.u[3] = b1hi.y;

        uint2 P0[2][4], P1[2][4];
        #pragma unroll
        for (int jh = 0; jh < 2; ++jh) {
            const int rrow = (jhalf*8 + tt*2 + jh)*16 + n;
            const float rj0 = r_lds[0][rrow];
            const float rj1 = r_lds[1][rrow];
            U8 af0, af1;
            #pragma unroll
            for (int qq = 0; qq < 4; ++qq) {
                const float h00 = fmaxf(rj0*rw1q[2*qq]   + rb1q[2*qq],   0.f);
                const float h01 = fmaxf(rj0*rw1q[2*qq+1] + rb1q[2*qq+1], 0.f);
                af0.u[qq] = pkbf(h00, h01);
                const float h10 = fmaxf(rj1*rw1q[2*qq]   + rb1q[2*qq],   0.f);
                const float h11 = fmaxf(rj1*rw1q[2*qq+1] + rb1q[2*qq+1], 0.f);
                af1.u[qq] = pkbf(h10, h11);
            }
            U8 afV;
            afV.u[0] = 0; afV.u[1] = 0; afV.u[2] = 0; afV.u[3] = 0;
            if (g == 0) {
                const uint2 xb = *(const uint2*)&xsbf[(j0 + jh*16 + n)*4];
                afV.u[0] = xb.x;
                afV.u[1] = xb.y;
            }
            #pragma unroll
            for (int t4 = 0; t4 < 4; ++t4) {
                f32x4 vv = __builtin_amdgcn_mfma_f32_16x16x32_bf16(afV.s, bv[t4], vzero, 0, 0, 0);
                f32x4 d0 = __builtin_amdgcn_mfma_f32_16x16x32_bf16(af0.s, bfrag[t4], cinit[t4], 0, 0, 0);
                f32x4 d1 = __builtin_amdgcn_mfma_f32_16x16x32_bf16(af1.s, bfrag[t4], cinit[t4], 0, 0, 0);
                P0[jh][t4].x = pkbf(d0[0]*vv[0], d0[1]*vv[1]);
                P0[jh][t4].y = pkbf(d0[2]*vv[2], d0[3]*vv[3]);
                P1[jh][t4].x = pkbf(d1[0]*vv[0], d1[1]*vv[1]);
                P1[jh][t4].y = pkbf(d1[2]*vv[2], d1[3]*vv[3]);
            }
        }

        #pragma unroll
        for (int t4 = 0; t4 < 4; ++t4) {
            U8 a20, a21;
            a20.u[0] = P0[0][t4].x; a20.u[1] = P0[0][t4].y;
            a20.u[2] = P0[1][t4].x; a20.u[3] = P0[1][t4].y;
            acc0[t4] = __builtin_amdgcn_mfma_f32_16x16x32_bf16(a20.s, bf20.s, acc0[t4], 0, 0, 0);
            a21.u[0] = P1[0][t4].x; a21.u[1] = P1[0][t4].y;
            a21.u[2] = P1[1][t4].x; a21.u[3] = P1[1][t4].y;
            acc1[t4] = __builtin_amdgcn_mfma_f32_16x16x32_bf16(a21.s, bf21.s, acc1[t4], 0, 0, 0);
        }
    }

    // ---- combine j-halves via LDS (alias aY slabs), square + msl-reduce ----
    __syncthreads();                          // all aY/r_lds reads complete
    float (*pacc0)[128] = (float(*)[128])aY0; // 8192 B <= 8448
    float (*pacc1)[128] = (float(*)[128])aY1;
    if (jhalf == 0) {
        #pragma unroll
        for (int t4 = 0; t4 < 4; ++t4)
            #pragma unroll
            for (int q = 0; q < 4; ++q) {
                pacc0[t4*4 + q][wcol*64 + lane] = acc0[t4][q];
                pacc1[t4*4 + q][wcol*64 + lane] = acc1[t4][q];
            }
    }
    __syncthreads();
    if (jhalf == 1) {
        #pragma unroll
        for (int ii = 0; ii < 2; ++ii) {
            f32x4* accp = ii ? acc1 : acc0;
            float (*paccp)[128] = ii ? pacc1 : pacc0;
            #pragma unroll
            for (int t4 = 0; t4 < 4; ++t4) {
                const int l = wcol*2 + (t4 >> 1);
                const int lo = l*l, hi = l*l + 2*l;
                const bool valid = (n >= lo) && (n <= hi);
                float s0 = accp[t4][0] + paccp[t4*4+0][wcol*64 + lane];
                float s1 = accp[t4][1] + paccp[t4*4+1][wcol*64 + lane];
                float s2 = accp[t4][2] + paccp[t4*4+2][wcol*64 + lane];
                float s3 = accp[t4][3] + paccp[t4*4+3][wcol*64 + lane];
                s0 = valid ? s0*s0 : 0.f;
                s1 = valid ? s1*s1 : 0.f;
                s2 = valid ? s2*s2 : 0.f;
                s3 = valid ? s3*s3 : 0.f;
                #pragma unroll
                for (int off = 1; off <= 8; off <<= 1) {
                    s0 += __shfl_xor(s0, off);
                    s1 += __shfl_xor(s1, off);
                    s2 += __shfl_xor(s2, off);
                    s3 += __shfl_xor(s3, off);
                }
                const float sv = (n==0) ? s0 : ((n==1) ? s1 : ((n==2) ? s2 : s3));
                if (n < 4) ssum_lds[ii][colbase + t4*16 + g*4 + n] = sv;
            }
        }
    }
    __syncthreads();
    {
        const int ii = tid >> 7;          // 0: i0, 1: i1
        const int lc = tid & 127;
        const float v = sqrtf(ssum_lds[ii][lc] + 1e-8f);
        atomicMax((unsigned*)&pmaxg[b*LC + lc], __float_as_uint(v));
        atomicAdd(&psumg[b*LC + lc], v);
    }
}

// ---------------- Kernel C: fc1 + LN + relu + fc2 (pooled read) ----------------
__global__ __launch_bounds__(512) void so3_post(
    const float* __restrict__ pmaxg,  // (B,128)
    const float* __restrict__ psumg,  // (B,128)
    const float* __restrict__ fc1_w,  // (256,256)
    const float* __restrict__ fc1_b,  // (256)
    const float* __restrict__ ln_g,   // (256)
    const float* __restrict__ ln_b,   // (256)
    const float* __restrict__ fc2_w,  // (256,40)
    const float* __restrict__ fc2_b,  // (40)
    float* __restrict__ outg)         // (B,40)
{
    const int b = blockIdx.x;
    const int t = threadIdx.x;
    __shared__ float pooled[256];
    __shared__ float pfc1[2][256];
    __shared__ float h1s[256];
    __shared__ float pf2[8][40];
    __shared__ float redA[8], redB[8];

    if (t < 128)      pooled[t] = pmaxg[b*LC + t];
    else if (t < 256) pooled[t] = psumg[b*LC + (t-128)] * (1.f/256.f);
    __syncthreads();

    {
        const int o = t & 255, kh = t >> 8;
        float acc = 0.f;
        for (int k = kh*128; k < kh*128 + 128; ++k)
            acc += pooled[k] * fc1_w[k*256 + o];
        pfc1[kh][o] = acc;
    }
    __syncthreads();

    float hval = 0.f;
    if (t < 256) hval = pfc1[0][t] + pfc1[1][t] + fc1_b[t];

    const int lane = t & 63, wid = t >> 6;
    float s1 = hval, s2 = hval*hval;
    #pragma unroll
    for (int off = 32; off >= 1; off >>= 1) {
        s1 += __shfl_xor(s1, off);
        s2 += __shfl_xor(s2, off);
    }
    if (lane == 0) { redA[wid] = s1; redB[wid] = s2; }
    __syncthreads();
    s1 = redA[0]+redA[1]+redA[2]+redA[3];
    s2 = redB[0]+redB[1]+redB[2]+redB[3];
    if (t < 256) {
        const float mu = s1 * (1.f/256.f);
        const float var = s2 * (1.f/256.f) - mu*mu;
        float v = (hval - mu) * rsqrtf(var + 1e-5f) * ln_g[t] + ln_b[t];
        h1s[t] = fmaxf(v, 0.f);
    }
    __syncthreads();

    if (t < 320) {
        const int o = t % 40, ks = t / 40;
        float acc = 0.f;
        for (int k = ks*32; k < ks*32 + 32; ++k)
            acc += h1s[k] * fc2_w[k*40 + o];
        pf2[ks][o] = acc;
    }
    __syncthreads();
    if (t < 40) {
        float o = fc2_b[t];
        #pragma unroll
        for (int ks = 0; ks < 8; ++ks) o += pf2[ks][t];
        outg[b*40 + t] = o;
    }
}

extern "C" void kernel_launch(void* const* d_in, const int* in_sizes, int n_in,
                              void* d_out, int out_size, void* d_ws, size_t ws_size,
                              hipStream_t stream) {
    const float* x     = (const float*)d_in[0];
    const float* Wq    = (const float*)d_in[1];
    const float* Wk    = (const float*)d_in[2];
    const float* Wv    = (const float*)d_in[3];
    const float* Rw1   = (const float*)d_in[4];
    const float* Rb1   = (const float*)d_in[5];
    const float* Rw2   = (const float*)d_in[6];
    const float* Rb2   = (const float*)d_in[7];
    const float* fc1_w = (const float*)d_in[8];
    const float* fc1_b = (const float*)d_in[9];
    const float* ln_g  = (const float*)d_in[10];
    const float* ln_b  = (const float*)d_in[11];
    const float* fc2_w = (const float*)d_in[12];
    const float* fc2_b = (const float*)d_in[13];
    float* out = (float*)d_out;

    float* ws = (float*)d_ws;
    float* pmaxg = ws;                       // 1024 f32
    float* psumg = pmaxg + BB*LC;            // 1024 f32
    short* RW2bf = (short*)(psumg + BB*LC);  // 4096 bf16
    float* WvT   = (float*)(RW2bf + 4096);   // 512 f32

    so3_init<<<1, 256, 0, stream>>>(Rw2, Wv, pmaxg, psumg, RW2bf, WvT);
    so3_main<<<BB*128, 256, 0, stream>>>(x, Wq, Wk, Rw1, Rb1, RW2bf, Rb2, WvT, pmaxg, psumg);
    so3_post<<<BB, 512, 0, stream>>>(pmaxg, psumg, fc1_w, fc1_b, ln_g, ln_b, fc2_w, fc2_b, out);
}

// Round 15
// 43.433 us; speedup vs baseline: 1.1192x; 1.1192x over previous
//
#include <hip/hip_runtime.h>
#include <hip/hip_bf16.h>

#define BB 8
#define NN 256
#define LC 128

typedef short short8 __attribute__((ext_vector_type(8)));
typedef float f32x4 __attribute__((ext_vector_type(4)));

union U8 { short8 s; unsigned u[4]; };

__device__ inline unsigned pkbf(float a, float b){
    __hip_bfloat162 h = __float22bfloat162_rn(make_float2(a, b));
    union { __hip_bfloat162 h2; unsigned u; } cv; cv.h2 = h; return cv.u;
}

// stage alpha*Y (bf16) for one j into a per-wave slab [msl][j], stride 264
__device__ inline void stage_aY(short* __restrict__ slab, int j, float a,
                                float dx, float dy, float dz, float r2)
{
    const float ir = rsqrtf(r2);
    const float ux = dx*ir, uy = dy*ir, uz = dz*ir;
    const float X2 = ux*ux, Y2 = uy*uy, Z2 = uz*uz;
    const float y0  = 0.28209479f;
    const float y1  = 0.48860251f*uy, y2 = 0.48860251f*uz, y3 = 0.48860251f*ux;
    const float y4  = 1.09254843f*ux*uy;
    const float y5  = 1.09254843f*uy*uz;
    const float y6  = 0.31539157f*(3.f*Z2 - 1.f);
    const float y7  = 1.09254843f*ux*uz;
    const float y8  = 0.54627422f*(X2 - Y2);
    const float y9  = 0.59004359f*uy*(3.f*X2 - Y2);
    const float y10 = 2.89061144f*ux*uy*uz;
    const float y11 = 0.45704579f*uy*(5.f*Z2 - 1.f);
    const float y12 = 0.37317633f*uz*(5.f*Z2 - 3.f);
    const float y13 = 0.45704579f*ux*(5.f*Z2 - 1.f);
    const float y14 = 1.44530572f*uz*(X2 - Y2);
    const float y15 = 0.59004359f*ux*(X2 - 3.f*Y2);
    #define ST2(mm, va, vb) { unsigned uu = pkbf((va)*a, (vb)*a); \
        slab[(mm)*264 + j] = (short)(uu & 0xffff); slab[(mm+1)*264 + j] = (short)(uu >> 16); }
    ST2(0,  y0,  y1)  ST2(2,  y2,  y3)
    ST2(4,  y4,  y5)  ST2(6,  y6,  y7)
    ST2(8,  y8,  y9)  ST2(10, y10, y11)
    ST2(12, y12, y13) ST2(14, y14, y15)
    #undef ST2
}

// ---------------- Kernel B: per-wave-independent main, 1 barrier total ----------------
// grid = BB*64 blocks; block = 4 waves; wave w owns i = (blk&63)*4 + w completely.
__global__ __launch_bounds__(256) void so3_main(
    const float* __restrict__ xg,     // (B,N,4)
    const float* __restrict__ Wq,     // (4,32)
    const float* __restrict__ Wk,     // (4,32)
    const float* __restrict__ Wv,     // (L,4,32)
    const float* __restrict__ Rw1,    // (32)
    const float* __restrict__ Rb1,    // (32)
    const float* __restrict__ Rw2,    // (32,128)
    const float* __restrict__ Rb2,    // (128)
    float* __restrict__ invg)         // (B,N,128)
{
    const int tid = threadIdx.x;          // 0..255
    const int blk = blockIdx.x;
    const int b = blk >> 6;
    const int iq = blk & 63;
    const int rowbase = b * NN;
    const int lane = tid & 63;
    const int w = tid >> 6;               // wave id; i = iq*4 + w
    const int n = lane & 15;
    const int g = lane >> 4;
    const int kbase = g * 8;
    const int i = iq*4 + w;

    __shared__ __align__(16) float xs[NN*4];     // 4 KB f32 x rows
    __shared__ short xsbf[NN*4];                 // 2 KB bf16 x rows
    __shared__ short aYs[4][16*264];             // per-wave alpha*Y slabs (33.8 KB)
    __shared__ float asum[4][256];               // per-wave alpha exchange / ssum scratch (4 KB)

    // ---- block-cooperative x staging (one row per thread) ----
    const float4 x4 = *(const float4*)&xg[(rowbase + tid)*4];
    *(float4*)&xs[tid*4] = x4;
    {
        uint2 xb;
        xb.x = pkbf(x4.x, x4.y);
        xb.y = pkbf(x4.z, x4.w);
        *(uint2*)&xsbf[tid*4] = xb;
    }
    const float4 xi = *(const float4*)&xg[(rowbase + i)*4];

    // ---- per-wave m[d] = lscale * sum_c q_c * Wk[d][c] (shfl only) ----
    float md0, md1, md2, md3;
    {
        const int c = lane & 31;
        const float qc = xi.x*Wq[c] + xi.y*Wq[32+c] + xi.z*Wq[64+c] + xi.w*Wq[96+c];
        md0 = qc*Wk[c]; md1 = qc*Wk[32+c]; md2 = qc*Wk[64+c]; md3 = qc*Wk[96+c];
        #pragma unroll
        for (int off = 16; off >= 1; off >>= 1) {
            md0 += __shfl_xor(md0, off);
            md1 += __shfl_xor(md1, off);
            md2 += __shfl_xor(md2, off);
            md3 += __shfl_xor(md3, off);
        }
        const float lscale = 0.17677669529663687f;  // 1/sqrt(32)
        md0 *= lscale; md1 *= lscale; md2 *= lscale; md3 *= lscale;
    }

    __syncthreads();   // the ONLY block barrier: xs/xsbf ready

    // ---- per-lane sweep: r and logits for j = 16s+n (covers all 256 j per wave) ----
    float r_reg[16], lgv[16];
    #pragma unroll
    for (int s = 0; s < 16; ++s) {
        const float4 xa = *(const float4*)&xs[(16*s + n)*4];
        const float ddx = xa.x - xi.x, ddy = xa.y - xi.y, ddz = xa.z - xi.z;
        const float r2 = ddx*ddx + ddy*ddy + ddz*ddz + 1e-8f;
        r_reg[s] = sqrtf(r2);
        lgv[s] = md0*xa.x + md1*xa.y + md2*xa.z + md3*xa.w;
    }

    // ---- per-wave softmax (reduce over n-groups; g-duplicates identical) ----
    float mx = lgv[0];
    #pragma unroll
    for (int s = 1; s < 16; ++s) mx = fmaxf(mx, lgv[s]);
    #pragma unroll
    for (int off = 1; off <= 8; off <<= 1) mx = fmaxf(mx, __shfl_xor(mx, off));
    float es = 0.f;
    float ev[16];
    #pragma unroll
    for (int s = 0; s < 16; ++s) { ev[s] = __expf(lgv[s] - mx); es += ev[s]; }
    #pragma unroll
    for (int off = 1; off <= 8; off <<= 1) es += __shfl_xor(es, off);
    const float invS = 1.0f / es;
    #pragma unroll
    for (int s = 0; s < 16; ++s) asum[w][16*s + n] = ev[s]*invS;

    asm volatile("s_waitcnt lgkmcnt(0)" ::: "memory");
    __builtin_amdgcn_sched_barrier(0);

    // ---- per-wave aY staging: lane (n,g) stages j = 64g + 16e + n ----
    short* slab = &aYs[w][0];
    #pragma unroll
    for (int e = 0; e < 4; ++e) {
        const int j = 64*g + 16*e + n;
        const float a = asum[w][j];
        const float4 xa = *(const float4*)&xs[j*4];
        const float ddx = xa.x - xi.x, ddy = xa.y - xi.y, ddz = xa.z - xi.z;
        const float r2 = ddx*ddx + ddy*ddy + ddz*ddz + 1e-8f;
        stage_aY(slab, j, a, ddx, ddy, ddz, r2);
    }

    float rw1q[8], rb1q[8];
    #pragma unroll
    for (int q = 0; q < 8; ++q) { rw1q[q] = Rw1[kbase+q]; rb1q[q] = Rb1[kbase+q]; }

    asm volatile("s_waitcnt lgkmcnt(0)" ::: "memory");
    __builtin_amdgcn_sched_barrier(0);

    const int boff = n*264 + 4*g;
    const f32x4 vzero = {0.f, 0.f, 0.f, 0.f};

    // ---- main loop: 2 col-halves x 8 j-tiles, barrier-free, per-wave ----
    #pragma unroll
    for (int h4 = 0; h4 < 2; ++h4) {
        short8 bfrag[4], bv[4];
        float rb2v[4];
        #pragma unroll
        for (int t4 = 0; t4 < 4; ++t4) {
            const int col = h4*64 + t4*16 + n;
            U8 bf;
            #pragma unroll
            for (int qq = 0; qq < 4; ++qq)
                bf.u[qq] = pkbf(Rw2[(kbase+2*qq)*LC + col], Rw2[(kbase+2*qq+1)*LC + col]);
            bfrag[t4] = bf.s;
            rb2v[t4] = Rb2[col];
            U8 z; z.u[0] = 0; z.u[1] = 0; z.u[2] = 0; z.u[3] = 0;
            if (g == 0) {
                const int l = (h4*64 + t4*16) >> 5;
                const int cc = (t4 & 1)*16 + n;
                z.u[0] = pkbf(Wv[l*128 + cc],      Wv[l*128 + 32 + cc]);
                z.u[1] = pkbf(Wv[l*128 + 64 + cc], Wv[l*128 + 96 + cc]);
            }
            bv[t4] = z.s;
        }

        f32x4 acc[4] = {};

        #pragma unroll
        for (int tt = 0; tt < 8; ++tt) {
            const int j0 = 32*tt;

            const uint2 blo = *(const uint2*)&slab[boff + j0];
            const uint2 bhi = *(const uint2*)&slab[boff + j0 + 16];
            U8 bf2;
            bf2.u[0] = blo.x; bf2.u[1] = blo.y; bf2.u[2] = bhi.x; bf2.u[3] = bhi.y;

            uint2 P[2][4];
            #pragma unroll
            for (int jh = 0; jh < 2; ++jh) {
                const float rj = r_reg[2*tt + jh];
                U8 af;
                #pragma unroll
                for (int qq = 0; qq < 4; ++qq) {
                    const float h0 = fmaxf(rj*rw1q[2*qq]   + rb1q[2*qq],   0.f);
                    const float h1 = fmaxf(rj*rw1q[2*qq+1] + rb1q[2*qq+1], 0.f);
                    af.u[qq] = pkbf(h0, h1);
                }
                U8 afV; afV.u[0] = 0; afV.u[1] = 0; afV.u[2] = 0; afV.u[3] = 0;
                if (g == 0) {
                    const uint2 xb = *(const uint2*)&xsbf[(j0 + 16*jh + n)*4];
                    afV.u[0] = xb.x; afV.u[1] = xb.y;
                }
                #pragma unroll
                for (int t4 = 0; t4 < 4; ++t4) {
                    f32x4 d  = __builtin_amdgcn_mfma_f32_16x16x32_bf16(af.s,  bfrag[t4], vzero, 0, 0, 0);
                    f32x4 vv = __builtin_amdgcn_mfma_f32_16x16x32_bf16(afV.s, bv[t4],    vzero, 0, 0, 0);
                    P[jh][t4].x = pkbf((d[0]+rb2v[t4])*vv[0], (d[1]+rb2v[t4])*vv[1]);
                    P[jh][t4].y = pkbf((d[2]+rb2v[t4])*vv[2], (d[3]+rb2v[t4])*vv[3]);
                }
            }

            #pragma unroll
            for (int t4 = 0; t4 < 4; ++t4) {
                U8 a2;
                a2.u[0] = P[0][t4].x; a2.u[1] = P[0][t4].y;
                a2.u[2] = P[1][t4].x; a2.u[3] = P[1][t4].y;
                acc[t4] = __builtin_amdgcn_mfma_f32_16x16x32_bf16(a2.s, bf2.s, acc[t4], 0, 0, 0);
            }
        }

        // ---- per-wave epilogue for this col-half ----
        #pragma unroll
        for (int t4 = 0; t4 < 4; ++t4) {
            const int l = h4*2 + (t4 >> 1);
            const int lo = l*l, hi = l*l + 2*l;
            const bool valid = (n >= lo) && (n <= hi);
            f32x4 aq = acc[t4];
            float s0 = valid ? aq[0]*aq[0] : 0.f;
            float s1 = valid ? aq[1]*aq[1] : 0.f;
            float s2 = valid ? aq[2]*aq[2] : 0.f;
            float s3 = valid ? aq[3]*aq[3] : 0.f;
            #pragma unroll
            for (int off = 1; off <= 8; off <<= 1) {
                s0 += __shfl_xor(s0, off);
                s1 += __shfl_xor(s1, off);
                s2 += __shfl_xor(s2, off);
                s3 += __shfl_xor(s3, off);
            }
            const float sv = (n==0) ? s0 : ((n==1) ? s1 : ((n==2) ? s2 : s3));
            if (n < 4) asum[w][h4*64 + t4*16 + g*4 + n] = sv;
        }
    }

    asm volatile("s_waitcnt lgkmcnt(0)" ::: "memory");
    __builtin_amdgcn_sched_barrier(0);
    {
        const float v0 = asum[w][lane];
        const float v1 = asum[w][lane + 64];
        float* dst = &invg[(size_t)(rowbase + i)*LC];
        dst[lane]      = sqrtf(v0 + 1e-8f);
        dst[lane + 64] = sqrtf(v1 + 1e-8f);
    }
}

// ---------------- Kernel C: pool (1024 threads) + fc1 + LN + relu + fc2 ----------------
__global__ __launch_bounds__(1024) void so3_post(
    const float* __restrict__ invg,   // (B,N,128)
    const float* __restrict__ fc1_w,  // (256,256)
    const float* __restrict__ fc1_b,  // (256)
    const float* __restrict__ ln_g,   // (256)
    const float* __restrict__ ln_b,   // (256)
    const float* __restrict__ fc2_w,  // (256,40)
    const float* __restrict__ fc2_b,  // (40)
    float* __restrict__ outg)         // (B,40)
{
    const int b = blockIdx.x;
    const int t = threadIdx.x;
    __shared__ float pm[8][128], ps[8][128];
    __shared__ float pooled[256];
    __shared__ float pfc1[2][256];
    __shared__ float h1s[256];
    __shared__ float pf2[8][40];
    __shared__ float redA[4], redB[4];

    {
        const int ig = t >> 7, lc = t & 127;
        float mxv = -1e30f, sm = 0.f;
        for (int i2 = ig; i2 < NN; i2 += 8) {
            const float v = invg[(size_t)(b*NN + i2)*LC + lc];
            mxv = fmaxf(mxv, v);
            sm += v;
        }
        pm[ig][lc] = mxv; ps[ig][lc] = sm;
    }
    __syncthreads();
    if (t < 128) {
        float m0 = pm[0][t];
        #pragma unroll
        for (int k = 1; k < 8; ++k) m0 = fmaxf(m0, pm[k][t]);
        pooled[t] = m0;
    } else if (t < 256) {
        const int lc = t - 128;
        float s0 = ps[0][lc];
        #pragma unroll
        for (int k = 1; k < 8; ++k) s0 += ps[k][lc];
        pooled[t] = s0 * (1.f/256.f);
    }
    __syncthreads();

    if (t < 512) {
        const int o = t & 255, kh = t >> 8;
        float acc = 0.f;
        for (int k = kh*128; k < kh*128 + 128; ++k)
            acc += pooled[k] * fc1_w[k*256 + o];
        pfc1[kh][o] = acc;
    }
    __syncthreads();

    float hval = 0.f;
    if (t < 256) hval = pfc1[0][t] + pfc1[1][t] + fc1_b[t];

    const int lane = t & 63, wid = t >> 6;
    float s1 = (t < 256) ? hval : 0.f;
    float s2 = (t < 256) ? hval*hval : 0.f;
    #pragma unroll
    for (int off = 32; off >= 1; off >>= 1) {
        s1 += __shfl_xor(s1, off);
        s2 += __shfl_xor(s2, off);
    }
    if (lane == 0 && wid < 4) { redA[wid] = s1; redB[wid] = s2; }
    __syncthreads();
    s1 = redA[0]+redA[1]+redA[2]+redA[3];
    s2 = redB[0]+redB[1]+redB[2]+redB[3];
    if (t < 256) {
        const float mu = s1 * (1.f/256.f);
        const float var = s2 * (1.f/256.f) - mu*mu;
        float v = (hval - mu) * rsqrtf(var + 1e-5f) * ln_g[t] + ln_b[t];
        h1s[t] = fmaxf(v, 0.f);
    }
    __syncthreads();

    if (t < 320) {
        const int o = t % 40, ks = t / 40;
        float acc = 0.f;
        for (int k = ks*32; k < ks*32 + 32; ++k)
            acc += h1s[k] * fc2_w[k*40 + o];
        pf2[ks][o] = acc;
    }
    __syncthreads();
    if (t < 40) {
        float o = fc2_b[t];
        #pragma unroll
        for (int ks = 0; ks < 8; ++ks) o += pf2[ks][t];
        outg[b*40 + t] = o;
    }
}

extern "C" void kernel_launch(void* const* d_in, const int* in_sizes, int n_in,
                              void* d_out, int out_size, void* d_ws, size_t ws_size,
                              hipStream_t stream) {
    const float* x     = (const float*)d_in[0];
    const float* Wq    = (const float*)d_in[1];
    const float* Wk    = (const float*)d_in[2];
    const float* Wv    = (const float*)d_in[3];
    const float* Rw1   = (const float*)d_in[4];
    const float* Rb1   = (const float*)d_in[5];
    const float* Rw2   = (const float*)d_in[6];
    const float* Rb2   = (const float*)d_in[7];
    const float* fc1_w = (const float*)d_in[8];
    const float* fc1_b = (const float*)d_in[9];
    const float* ln_g  = (const float*)d_in[10];
    const float* ln_b  = (const float*)d_in[11];
    const float* fc2_w = (const float*)d_in[12];
    const float* fc2_b = (const float*)d_in[13];
    float* out = (float*)d_out;

    float* invg = (float*)d_ws;            // B*N*128 = 262144 f32

    so3_main<<<BB*64, 256, 0, stream>>>(x, Wq, Wk, Wv, Rw1, Rb1, Rw2, Rb2, invg);
    so3_post<<<BB, 1024, 0, stream>>>(invg, fc1_w, fc1_b, ln_g, ln_b, fc2_w, fc2_b, out);
}